// Round 1
// baseline (283.295 us; speedup 1.0000x reference)
//
#include <hip/hip_runtime.h>
#include <hip/hip_bf16.h>
#include <math.h>

typedef __hip_bfloat16 bf16;
typedef float f32x4 __attribute__((ext_vector_type(4)));
typedef short s16x8 __attribute__((ext_vector_type(8)));

#define NB 2
#define SEQ 2048
#define HID 1024
#define NHEAD 16
#define HD 64
#define BH (NB * NHEAD)      // 32
#define MROWS (NB * SEQ)     // 4096

static __device__ __forceinline__ f32x4 mfma16(s16x8 a, s16x8 b, f32x4 c) {
  return __builtin_amdgcn_mfma_f32_16x16x32_bf16(a, b, c, 0, 0, 0);
}

static __device__ __forceinline__ void gload_lds16(const bf16* g, bf16* l) {
  __builtin_amdgcn_global_load_lds((const __attribute__((address_space(1))) void*)g,
                                   (__attribute__((address_space(3))) void*)l, 16, 0, 0);
}

// ---------------- fp32 -> bf16 conversion ----------------
__global__ __launch_bounds__(256) void f2b_kernel(const float* __restrict__ src,
                                                  bf16* __restrict__ dst, int n) {
  int i = (blockIdx.x * 256 + threadIdx.x) * 4;
  if (i >= n) return;
  float4 v = *(const float4*)(src + i);
  bf16 a0 = __float2bfloat16(v.x), a1 = __float2bfloat16(v.y);
  bf16 a2 = __float2bfloat16(v.z), a3 = __float2bfloat16(v.w);
  ushort4 u;
  u.x = *(const unsigned short*)&a0;
  u.y = *(const unsigned short*)&a1;
  u.z = *(const unsigned short*)&a2;
  u.w = *(const unsigned short*)&a3;
  *(ushort4*)(dst + i) = u;
}

// ---------------- RoPE tables: cos/sin [SEQ][32] ----------------
__global__ __launch_bounds__(256) void rope_tab_kernel(float* __restrict__ ct, float* __restrict__ st) {
  int i = blockIdx.x * 256 + threadIdx.x;   // SEQ*32 = 65536
  int s = i >> 5, j = i & 31;
  // inv_freq = 10000^(-2j/64)
  float inv = expf(-(float)(2 * j) * (9.210340371976184f / 64.0f));
  float ang = (float)s * inv;
  float sn, cs;
  sincosf(ang, &sn, &cs);
  ct[i] = cs;
  st[i] = sn;
}

// ---------------- RoPE apply (in-place on Q and K, layout [BH][SEQ][HD] bf16) ----------------
__global__ __launch_bounds__(256) void rope_kernel(bf16* __restrict__ Q, bf16* __restrict__ K,
                                                   const float* __restrict__ ct,
                                                   const float* __restrict__ st) {
  int idx = blockIdx.x * 256 + threadIdx.x;   // 2 * BH*SEQ*32 = 4M
  bf16* P = (idx >= (1 << 21)) ? K : Q;
  int r = idx & ((1 << 21) - 1);
  int bh = r >> 16;
  int s = (r >> 5) & (SEQ - 1);
  int j = r & 31;
  size_t base = ((size_t)bh * SEQ + s) * HD;
  float c = ct[s * 32 + j], sn = st[s * 32 + j];
  float x0 = __bfloat162float(P[base + j]);
  float x1 = __bfloat162float(P[base + 32 + j]);
  P[base + j]      = __float2bfloat16(x0 * c - x1 * sn);
  P[base + 32 + j] = __float2bfloat16(x1 * c + x0 * sn);
}

// ---------------- GEMM: C[m,n] = sum_k A[m,k]*B[n,k]  (A:[M,K], B:[N,K], both bf16 row-major)
// MODE 0: scatter-write bf16 Q/K/V in [BH][SEQ][HD] layout (N = 3*HID)
// MODE 1: write fp32 C[m*N + n]
template <int MODE>
__global__ __launch_bounds__(256) void gemm_bt(const bf16* __restrict__ A, const bf16* __restrict__ Bm,
                                               float* __restrict__ C,
                                               bf16* __restrict__ Qb, bf16* __restrict__ Kb,
                                               bf16* __restrict__ Vb,
                                               int M, int N, int K) {
  __shared__ __align__(16) bf16 As[128][32];
  __shared__ __align__(16) bf16 Bs[128][32];
  const int tid = threadIdx.x, lane = tid & 63, wid = tid >> 6;
  const int wm = wid >> 1, wn = wid & 1;
  const int tm = blockIdx.y * 128, tn = blockIdx.x * 128;
  const int lrow = lane >> 2;          // 0..15
  const int lcol = (lane & 3) * 8;     // element offset in k

  f32x4 acc[4][4];
#pragma unroll
  for (int i = 0; i < 4; ++i)
#pragma unroll
    for (int j = 0; j < 4; ++j) acc[i][j] = (f32x4){0.f, 0.f, 0.f, 0.f};

  for (int k0 = 0; k0 < K; k0 += 32) {
    __syncthreads();
    {
      int r0 = wid * 32;
      gload_lds16(A  + (size_t)(tm + r0 +      lrow) * K + k0 + lcol, &As[r0][0]);
      gload_lds16(A  + (size_t)(tm + r0 + 16 + lrow) * K + k0 + lcol, &As[r0 + 16][0]);
      gload_lds16(Bm + (size_t)(tn + r0 +      lrow) * K + k0 + lcol, &Bs[r0][0]);
      gload_lds16(Bm + (size_t)(tn + r0 + 16 + lrow) * K + k0 + lcol, &Bs[r0 + 16][0]);
    }
    __syncthreads();
    s16x8 af[4], bfr[4];
#pragma unroll
    for (int mi = 0; mi < 4; ++mi)
      af[mi] = *(const s16x8*)&As[wm * 64 + mi * 16 + (lane & 15)][(lane >> 4) * 8];
#pragma unroll
    for (int ni = 0; ni < 4; ++ni)
      bfr[ni] = *(const s16x8*)&Bs[wn * 64 + ni * 16 + (lane & 15)][(lane >> 4) * 8];
#pragma unroll
    for (int mi = 0; mi < 4; ++mi)
#pragma unroll
      for (int ni = 0; ni < 4; ++ni)
        acc[mi][ni] = mfma16(af[mi], bfr[ni], acc[mi][ni]);
  }

#pragma unroll
  for (int mi = 0; mi < 4; ++mi) {
#pragma unroll
    for (int ni = 0; ni < 4; ++ni) {
#pragma unroll
      for (int r = 0; r < 4; ++r) {
        int row = tm + wm * 64 + mi * 16 + (lane >> 4) * 4 + r;
        int col = tn + wn * 64 + ni * 16 + (lane & 15);
        float v = acc[mi][ni][r];
        if (MODE == 0) {
          int t = col >> 10, c = col & (HID - 1);
          int h = c >> 6, d = c & 63;
          int b = row >> 11, s = row & (SEQ - 1);
          bf16* dst = (t == 0) ? Qb : ((t == 1) ? Kb : Vb);
          dst[(((size_t)(b * NHEAD + h)) * SEQ + s) * HD + d] = __float2bfloat16(v);
        } else {
          C[(size_t)row * N + col] = v;
        }
      }
    }
  }
}

// ---------------- Flash attention: Q,K,V [BH][SEQ][HD] bf16 -> ctx [NB][SEQ][HID] bf16 ----------------
__global__ __launch_bounds__(256) void attn_kernel(const bf16* __restrict__ Q, const bf16* __restrict__ K,
                                                   const bf16* __restrict__ V, bf16* __restrict__ ctx) {
  __shared__ __align__(16) bf16 Qs[64][64];
  __shared__ __align__(16) bf16 Ks[64][64];
  __shared__ __align__(16) bf16 Vt[64][64];     // transposed: Vt[d][kv]
  __shared__ __align__(16) bf16 Ps[4][16][64];  // per-wave P staging
  const int tid = threadIdx.x, lane = tid & 63, wid = tid >> 6;
  const int qb = blockIdx.x, bh = blockIdx.y;

  const bf16* Qp = Q + ((size_t)bh * SEQ + qb * 64) * HD;
#pragma unroll
  for (int it = 0; it < 2; ++it) {
    int idx = tid + it * 256;
    int row = idx >> 3, c8 = (idx & 7) * 8;
    *(int4*)&Qs[row][c8] = *(const int4*)&Qp[row * HD + c8];
  }
  __syncthreads();
  s16x8 qf[2];
#pragma unroll
  for (int ks = 0; ks < 2; ++ks)
    qf[ks] = *(const s16x8*)&Qs[wid * 16 + (lane & 15)][ks * 32 + (lane >> 4) * 8];

  float mrow[4], lrow[4];
  f32x4 acc[4];
#pragma unroll
  for (int r = 0; r < 4; ++r) { mrow[r] = -1e30f; lrow[r] = 0.f; }
#pragma unroll
  for (int nf = 0; nf < 4; ++nf) acc[nf] = (f32x4){0.f, 0.f, 0.f, 0.f};

  for (int kvt = 0; kvt < SEQ / 64; ++kvt) {
    __syncthreads();
    const bf16* Kp = K + ((size_t)bh * SEQ + kvt * 64) * HD;
    const bf16* Vp = V + ((size_t)bh * SEQ + kvt * 64) * HD;
#pragma unroll
    for (int it = 0; it < 2; ++it) {
      int idx = tid + it * 256;
      int row = idx >> 3, c8 = (idx & 7) * 8;
      *(int4*)&Ks[row][c8] = *(const int4*)&Kp[row * HD + c8];
      int4 vv = *(const int4*)&Vp[row * HD + c8];
      const bf16* pv = (const bf16*)&vv;
#pragma unroll
      for (int j = 0; j < 8; ++j) Vt[c8 + j][row] = pv[j];
    }
    __syncthreads();

    // S = Q K^T / 8 : each wave computes 16 q-rows x 64 kv
    f32x4 sf[4];
#pragma unroll
    for (int nf = 0; nf < 4; ++nf) {
      f32x4 s = (f32x4){0.f, 0.f, 0.f, 0.f};
#pragma unroll
      for (int ks = 0; ks < 2; ++ks) {
        s16x8 kf = *(const s16x8*)&Ks[nf * 16 + (lane & 15)][ks * 32 + (lane >> 4) * 8];
        s = mfma16(qf[ks], kf, s);
      }
#pragma unroll
      for (int r = 0; r < 4; ++r) s[r] *= 0.125f;
      sf[nf] = s;
    }

    // online softmax (rows owned by 16-lane groups)
    float rm[4];
#pragma unroll
    for (int r = 0; r < 4; ++r) {
      float v = fmaxf(fmaxf(sf[0][r], sf[1][r]), fmaxf(sf[2][r], sf[3][r]));
#pragma unroll
      for (int off = 1; off < 16; off <<= 1) v = fmaxf(v, __shfl_xor(v, off));
      rm[r] = v;
    }
    float corr[4];
#pragma unroll
    for (int r = 0; r < 4; ++r) {
      float mn = fmaxf(mrow[r], rm[r]);
      corr[r] = __expf(mrow[r] - mn);
      mrow[r] = mn;
    }
#pragma unroll
    for (int nf = 0; nf < 4; ++nf)
#pragma unroll
      for (int r = 0; r < 4; ++r) sf[nf][r] = __expf(sf[nf][r] - mrow[r]);
    float rs[4];
#pragma unroll
    for (int r = 0; r < 4; ++r) {
      float v = sf[0][r] + sf[1][r] + sf[2][r] + sf[3][r];
#pragma unroll
      for (int off = 1; off < 16; off <<= 1) v += __shfl_xor(v, off);
      rs[r] = v;
      lrow[r] = lrow[r] * corr[r] + v;
    }
#pragma unroll
    for (int nf = 0; nf < 4; ++nf)
#pragma unroll
      for (int r = 0; r < 4; ++r) acc[nf][r] *= corr[r];

    // P -> LDS (C-layout to A-layout redistribution), then PV
#pragma unroll
    for (int nf = 0; nf < 4; ++nf)
#pragma unroll
      for (int r = 0; r < 4; ++r)
        Ps[wid][(lane >> 4) * 4 + r][nf * 16 + (lane & 15)] = __float2bfloat16(sf[nf][r]);
    s16x8 pf[2];
#pragma unroll
    for (int ks = 0; ks < 2; ++ks)
      pf[ks] = *(const s16x8*)&Ps[wid][lane & 15][ks * 32 + (lane >> 4) * 8];
#pragma unroll
    for (int nf = 0; nf < 4; ++nf) {
#pragma unroll
      for (int ks = 0; ks < 2; ++ks) {
        s16x8 vf = *(const s16x8*)&Vt[nf * 16 + (lane & 15)][ks * 32 + (lane >> 4) * 8];
        acc[nf] = mfma16(pf[ks], vf, acc[nf]);
      }
    }
  }

  // epilogue: ctx[b][s][h*64+d] = acc/l
  int b = bh >> 4, h = bh & (NHEAD - 1);
#pragma unroll
  for (int nf = 0; nf < 4; ++nf) {
#pragma unroll
    for (int r = 0; r < 4; ++r) {
      int s = qb * 64 + wid * 16 + (lane >> 4) * 4 + r;
      int d = nf * 16 + (lane & 15);
      float o = acc[nf][r] / lrow[r];
      ctx[((size_t)b * SEQ + s) * HID + h * HD + d] = __float2bfloat16(o);
    }
  }
}

extern "C" void kernel_launch(void* const* d_in, const int* in_sizes, int n_in,
                              void* d_out, int out_size, void* d_ws, size_t ws_size,
                              hipStream_t stream) {
  const float* X  = (const float*)d_in[0];
  const float* Wq = (const float*)d_in[1];
  const float* Wk = (const float*)d_in[2];
  const float* Wv = (const float*)d_in[3];
  const float* Wo = (const float*)d_in[4];

  char* p = (char*)d_ws;
  bf16* Xb   = (bf16*)p; p += (size_t)MROWS * HID * 2;
  bf16* Wqkv = (bf16*)p; p += (size_t)3 * HID * HID * 2;
  bf16* Wob  = (bf16*)p; p += (size_t)HID * HID * 2;
  bf16* Qb   = (bf16*)p; p += (size_t)BH * SEQ * HD * 2;
  bf16* Kb   = (bf16*)p; p += (size_t)BH * SEQ * HD * 2;
  bf16* Vb   = (bf16*)p; p += (size_t)BH * SEQ * HD * 2;
  bf16* Cb   = (bf16*)p; p += (size_t)MROWS * HID * 2;
  float* ct  = (float*)p; p += (size_t)SEQ * 32 * 4;
  float* st  = (float*)p; p += (size_t)SEQ * 32 * 4;

  // conversions
  f2b_kernel<<<(MROWS * HID) / 1024, 256, 0, stream>>>(X, Xb, MROWS * HID);
  f2b_kernel<<<(HID * HID) / 1024, 256, 0, stream>>>(Wq, Wqkv, HID * HID);
  f2b_kernel<<<(HID * HID) / 1024, 256, 0, stream>>>(Wk, Wqkv + (size_t)HID * HID, HID * HID);
  f2b_kernel<<<(HID * HID) / 1024, 256, 0, stream>>>(Wv, Wqkv + (size_t)2 * HID * HID, HID * HID);
  f2b_kernel<<<(HID * HID) / 1024, 256, 0, stream>>>(Wo, Wob, HID * HID);
  rope_tab_kernel<<<(SEQ * 32) / 256, 256, 0, stream>>>(ct, st);

  // QKV projection: [4096 x 3072] = Xb @ Wqkv^T, scatter to Q/K/V
  gemm_bt<0><<<dim3(3 * HID / 128, MROWS / 128), 256, 0, stream>>>(
      Xb, Wqkv, nullptr, Qb, Kb, Vb, MROWS, 3 * HID, HID);

  // RoPE on Q and K
  rope_kernel<<<(2 * BH * SEQ * 32) / 256, 256, 0, stream>>>(Qb, Kb, ct, st);

  // attention
  attn_kernel<<<dim3(SEQ / 64, BH), 256, 0, stream>>>(Qb, Kb, Vb, Cb);

  // output projection: [4096 x 1024] = Cb @ Wob^T -> fp32 out
  gemm_bt<1><<<dim3(HID / 128, MROWS / 128), 256, 0, stream>>>(
      Cb, Wob, (float*)d_out, nullptr, nullptr, nullptr, MROWS, HID, HID);
}

// Round 2
// 209.504 us; speedup vs baseline: 1.3522x; 1.3522x over previous
//
#include <hip/hip_runtime.h>
#include <hip/hip_bf16.h>
#include <math.h>

typedef __hip_bfloat16 bf16;
typedef float f32x4 __attribute__((ext_vector_type(4)));
typedef short s16x8 __attribute__((ext_vector_type(8)));

#define NB 2
#define SEQ 2048
#define HID 1024
#define NHEAD 16
#define HD 64
#define BH (NB * NHEAD)      // 32
#define MROWS (NB * SEQ)     // 4096

static __device__ __forceinline__ f32x4 mfma16(s16x8 a, s16x8 b, f32x4 c) {
  return __builtin_amdgcn_mfma_f32_16x16x32_bf16(a, b, c, 0, 0, 0);
}

static __device__ __forceinline__ void gload_lds16(const bf16* g, bf16* l) {
  __builtin_amdgcn_global_load_lds((const __attribute__((address_space(1))) void*)g,
                                   (__attribute__((address_space(3))) void*)l, 16, 0, 0);
}

// ---------------- fp32 -> bf16 conversion (hidden states) ----------------
__global__ __launch_bounds__(256) void f2b_kernel(const float* __restrict__ src,
                                                  bf16* __restrict__ dst, int n) {
  int i = (blockIdx.x * 256 + threadIdx.x) * 4;
  if (i >= n) return;
  float4 v = *(const float4*)(src + i);
  bf16 a0 = __float2bfloat16(v.x), a1 = __float2bfloat16(v.y);
  bf16 a2 = __float2bfloat16(v.z), a3 = __float2bfloat16(v.w);
  ushort4 u;
  u.x = *(const unsigned short*)&a0;
  u.y = *(const unsigned short*)&a1;
  u.z = *(const unsigned short*)&a2;
  u.w = *(const unsigned short*)&a3;
  *(ushort4*)(dst + i) = u;
}

// ---------------- fused weight conversions (Wq,Wk,Wv -> Wqkv; Wo -> Wob) ----------------
__global__ __launch_bounds__(256) void w4b_kernel(const float* __restrict__ wq, const float* __restrict__ wk,
                                                  const float* __restrict__ wv, const float* __restrict__ wo,
                                                  bf16* __restrict__ wqkv, bf16* __restrict__ wob) {
  int wsel = blockIdx.y;
  const float* src = (wsel == 0) ? wq : (wsel == 1) ? wk : (wsel == 2) ? wv : wo;
  bf16* dst = (wsel < 3) ? (wqkv + (size_t)wsel * HID * HID) : wob;
  int i = (blockIdx.x * 256 + threadIdx.x) * 4;
  float4 v = *(const float4*)(src + i);
  bf16 a0 = __float2bfloat16(v.x), a1 = __float2bfloat16(v.y);
  bf16 a2 = __float2bfloat16(v.z), a3 = __float2bfloat16(v.w);
  ushort4 u;
  u.x = *(const unsigned short*)&a0;
  u.y = *(const unsigned short*)&a1;
  u.z = *(const unsigned short*)&a2;
  u.w = *(const unsigned short*)&a3;
  *(ushort4*)(dst + i) = u;
}

// ---------------- RoPE tables: cos/sin [SEQ][32] ----------------
__global__ __launch_bounds__(256) void rope_tab_kernel(float* __restrict__ ct, float* __restrict__ st) {
  int i = blockIdx.x * 256 + threadIdx.x;   // SEQ*32 = 65536
  int s = i >> 5, j = i & 31;
  float inv = expf(-(float)(2 * j) * (9.210340371976184f / 64.0f));
  float ang = (float)s * inv;
  float sn, cs;
  sincosf(ang, &sn, &cs);
  ct[i] = cs;
  st[i] = sn;
}

// ---------------- V transpose: V[bh][s][d] -> Vt[bh][d][s] ----------------
__global__ __launch_bounds__(256) void vtrans_kernel(const bf16* __restrict__ V, bf16* __restrict__ Vt) {
  __shared__ bf16 T[64][65];
  const int tid = threadIdx.x;
  const int bh = blockIdx.y, s0 = blockIdx.x * 64;
  const bf16* Vp = V + ((size_t)bh * SEQ + s0) * HD;
#pragma unroll
  for (int it = 0; it < 2; ++it) {
    int idx = tid + it * 256;
    int r = idx >> 3, c8 = (idx & 7) * 8;
    int4 vv = *(const int4*)&Vp[r * HD + c8];
    const bf16* pv = (const bf16*)&vv;
#pragma unroll
    for (int j = 0; j < 8; ++j) T[r][c8 + j] = pv[j];
  }
  __syncthreads();
#pragma unroll
  for (int it = 0; it < 2; ++it) {
    int idx = tid + it * 256;
    int d = idx >> 3, sc = (idx & 7) * 8;
    bf16 tmp[8];
#pragma unroll
    for (int j = 0; j < 8; ++j) tmp[j] = T[sc + j][d];
    *(int4*)&Vt[((size_t)bh * HD + d) * SEQ + s0 + sc] = *(const int4*)tmp;
  }
}

// ---------------- GEMM: C[m,n] = sum_k A[m,k]*B[n,k]
// MODE 0: fused RoPE on Q/K cols, scatter bf16 Q/K/V ([BH][SEQ][HD])
// MODE 1: fp32 C
template <int MODE>
__global__ __launch_bounds__(256) void gemm_bt(const bf16* __restrict__ A, const bf16* __restrict__ Bm,
                                               float* __restrict__ C,
                                               bf16* __restrict__ Qb, bf16* __restrict__ Kb,
                                               bf16* __restrict__ Vb,
                                               const float* __restrict__ ct, const float* __restrict__ st,
                                               int M, int N, int K) {
  __shared__ __align__(16) bf16 As[128][32];
  __shared__ __align__(16) bf16 Bs[128][32];
  const int tid = threadIdx.x, lane = tid & 63, wid = tid >> 6;
  const int wm = wid >> 1, wn = wid & 1;
  const int tm = blockIdx.y * 128, tn = blockIdx.x * 128;
  const int lrow = lane >> 2;
  const int lcol = (lane & 3) * 8;

  f32x4 acc[4][4];
#pragma unroll
  for (int i = 0; i < 4; ++i)
#pragma unroll
    for (int j = 0; j < 4; ++j) acc[i][j] = (f32x4){0.f, 0.f, 0.f, 0.f};

  for (int k0 = 0; k0 < K; k0 += 32) {
    __syncthreads();
    {
      int r0 = wid * 32;
      gload_lds16(A  + (size_t)(tm + r0 +      lrow) * K + k0 + lcol, &As[r0][0]);
      gload_lds16(A  + (size_t)(tm + r0 + 16 + lrow) * K + k0 + lcol, &As[r0 + 16][0]);
      gload_lds16(Bm + (size_t)(tn + r0 +      lrow) * K + k0 + lcol, &Bs[r0][0]);
      gload_lds16(Bm + (size_t)(tn + r0 + 16 + lrow) * K + k0 + lcol, &Bs[r0 + 16][0]);
    }
    __syncthreads();
    s16x8 af[4], bfr[4];
#pragma unroll
    for (int mi = 0; mi < 4; ++mi)
      af[mi] = *(const s16x8*)&As[wm * 64 + mi * 16 + (lane & 15)][(lane >> 4) * 8];
#pragma unroll
    for (int ni = 0; ni < 4; ++ni)
      bfr[ni] = *(const s16x8*)&Bs[wn * 64 + ni * 16 + (lane & 15)][(lane >> 4) * 8];
#pragma unroll
    for (int mi = 0; mi < 4; ++mi)
#pragma unroll
      for (int ni = 0; ni < 4; ++ni)
        acc[mi][ni] = mfma16(af[mi], bfr[ni], acc[mi][ni]);
  }

  // fused RoPE for Q/K tiles (whole block is one of Q/K/V since 1024 % 128 == 0)
  if (MODE == 0) {
    const int tblk = tn >> 10;
    if (tblk < 2) {
#pragma unroll
      for (int mi = 0; mi < 4; ++mi) {
#pragma unroll
        for (int r = 0; r < 4; ++r) {
          int row = tm + wm * 64 + mi * 16 + (lane >> 4) * 4 + r;
          int s = row & (SEQ - 1);
#pragma unroll
          for (int p = 0; p < 2; ++p) {
            int j = p * 16 + (lane & 15);   // = d (0..31)
            float c = ct[s * 32 + j], sn = st[s * 32 + j];
            float x0 = acc[mi][p][r], x1 = acc[mi][p + 2][r];
            acc[mi][p][r]     = x0 * c - x1 * sn;
            acc[mi][p + 2][r] = x1 * c + x0 * sn;
          }
        }
      }
    }
  }

#pragma unroll
  for (int mi = 0; mi < 4; ++mi) {
#pragma unroll
    for (int ni = 0; ni < 4; ++ni) {
#pragma unroll
      for (int r = 0; r < 4; ++r) {
        int row = tm + wm * 64 + mi * 16 + (lane >> 4) * 4 + r;
        int col = tn + wn * 64 + ni * 16 + (lane & 15);
        float v = acc[mi][ni][r];
        if (MODE == 0) {
          int t = col >> 10, c = col & (HID - 1);
          int h = c >> 6, d = c & 63;
          int b = row >> 11, s = row & (SEQ - 1);
          bf16* dst = (t == 0) ? Qb : ((t == 1) ? Kb : Vb);
          dst[(((size_t)(b * NHEAD + h)) * SEQ + s) * HD + d] = __float2bfloat16(v);
        } else {
          C[(size_t)row * N + col] = v;
        }
      }
    }
  }
}

// ---------------- Flash attention ----------------
// Q,K: [BH][SEQ][64] bf16 ; Vt: [BH][64][SEQ] bf16 ; out ctx: [NB][SEQ][HID] bf16
// LDS tiles XOR-swizzled: 16B slot' = slot ^ (row&7); staging pre-swizzles the
// GLOBAL source address (global_load_lds writes linearly), reads apply same XOR.
__global__ __launch_bounds__(256) void attn_kernel(const bf16* __restrict__ Q, const bf16* __restrict__ K,
                                                   const bf16* __restrict__ Vt, bf16* __restrict__ ctx) {
  __shared__ __align__(16) bf16 S[4096 + 8192 + 8192];  // QsPs | Ks[2] | Vs[2]
  bf16* QsPs = S;
  bf16* Ks = S + 4096;
  bf16* Vs = S + 4096 + 8192;
  const int tid = threadIdx.x, l = tid & 63, w = tid >> 6;
  const int qb = blockIdx.x, bh = blockIdx.y;

  const bf16* Qp  = Q  + ((size_t)bh * SEQ + qb * 64) * HD;
  const bf16* Kp0 = K  + (size_t)bh * SEQ * HD;
  const bf16* Vp0 = Vt + (size_t)bh * HD * SEQ;

  // stage Q tile + first K/V tile (swizzled source, linear LDS dest)
#pragma unroll
  for (int it = 0; it < 2; ++it) {
    int cb = (it * 4 + w) * 64;
    int row = (cb + l) >> 3;
    int sc = ((l & 7) ^ (row & 7)) * 8;
    gload_lds16(Qp + row * HD + sc, QsPs + cb * 8);
    gload_lds16(Kp0 + (size_t)row * HD + sc, Ks + cb * 8);
    gload_lds16(Vp0 + (size_t)row * SEQ + sc, Vs + cb * 8);
  }
  __syncthreads();

  s16x8 qf[2];
#pragma unroll
  for (int ks = 0; ks < 2; ++ks) {
    int row = w * 16 + (l & 15);
    int slot = (ks * 4 + (l >> 4)) ^ (row & 7);
    qf[ks] = *(const s16x8*)(QsPs + row * 64 + slot * 8);
  }

  float mrow[4], lrow[4];
  f32x4 acc[4];
#pragma unroll
  for (int r = 0; r < 4; ++r) { mrow[r] = -1e30f; lrow[r] = 0.f; }
#pragma unroll
  for (int nf = 0; nf < 4; ++nf) acc[nf] = (f32x4){0.f, 0.f, 0.f, 0.f};

  const int NT = SEQ / 64;
  for (int kvt = 0; kvt < NT; ++kvt) {
    const int cur = kvt & 1;
    // prefetch next K/V tile into the other buffer
    if (kvt + 1 < NT) {
      const bf16* Kp = Kp0 + (size_t)(kvt + 1) * 64 * HD;
      const bf16* Vp = Vp0 + (kvt + 1) * 64;
      bf16* Kd = Ks + (1 - cur) * 4096;
      bf16* Vd = Vs + (1 - cur) * 4096;
#pragma unroll
      for (int it = 0; it < 2; ++it) {
        int cb = (it * 4 + w) * 64;
        int row = (cb + l) >> 3;
        int sc = ((l & 7) ^ (row & 7)) * 8;
        gload_lds16(Kp + (size_t)row * HD + sc, Kd + cb * 8);
        gload_lds16(Vp + (size_t)row * SEQ + sc, Vd + cb * 8);
      }
    }
    const bf16* Kc = Ks + cur * 4096;
    const bf16* Vc = Vs + cur * 4096;

    // S = Q K^T / 8
    f32x4 sf[4];
    __builtin_amdgcn_s_setprio(1);
#pragma unroll
    for (int nf = 0; nf < 4; ++nf) {
      f32x4 s = (f32x4){0.f, 0.f, 0.f, 0.f};
      int row = nf * 16 + (l & 15);
#pragma unroll
      for (int ks = 0; ks < 2; ++ks) {
        int slot = (ks * 4 + (l >> 4)) ^ (row & 7);
        s16x8 kf = *(const s16x8*)(Kc + row * 64 + slot * 8);
        s = mfma16(qf[ks], kf, s);
      }
#pragma unroll
      for (int r = 0; r < 4; ++r) s[r] *= 0.125f;
      sf[nf] = s;
    }
    __builtin_amdgcn_s_setprio(0);

    // online softmax (16-lane row groups)
    float rm[4];
#pragma unroll
    for (int r = 0; r < 4; ++r) {
      float v = fmaxf(fmaxf(sf[0][r], sf[1][r]), fmaxf(sf[2][r], sf[3][r]));
#pragma unroll
      for (int off = 1; off < 16; off <<= 1) v = fmaxf(v, __shfl_xor(v, off));
      rm[r] = v;
    }
    float corr[4];
#pragma unroll
    for (int r = 0; r < 4; ++r) {
      float mn = fmaxf(mrow[r], rm[r]);
      corr[r] = __expf(mrow[r] - mn);
      mrow[r] = mn;
    }
#pragma unroll
    for (int nf = 0; nf < 4; ++nf)
#pragma unroll
      for (int r = 0; r < 4; ++r) sf[nf][r] = __expf(sf[nf][r] - mrow[r]);
#pragma unroll
    for (int r = 0; r < 4; ++r) {
      float v = sf[0][r] + sf[1][r] + sf[2][r] + sf[3][r];
#pragma unroll
      for (int off = 1; off < 16; off <<= 1) v += __shfl_xor(v, off);
      lrow[r] = lrow[r] * corr[r] + v;
    }
#pragma unroll
    for (int nf = 0; nf < 4; ++nf)
#pragma unroll
      for (int r = 0; r < 4; ++r) acc[nf][r] *= corr[r];

    // P -> per-wave LDS (swizzled; aliases dead Q rows of this wave), reload as A-frag
#pragma unroll
    for (int nf = 0; nf < 4; ++nf)
#pragma unroll
      for (int r = 0; r < 4; ++r) {
        int row = (l >> 4) * 4 + r;
        int col = nf * 16 + (l & 15);
        int slot = (col >> 3) ^ (row & 7);
        QsPs[w * 1024 + row * 64 + slot * 8 + (col & 7)] = __float2bfloat16(sf[nf][r]);
      }
    s16x8 pf[2];
#pragma unroll
    for (int ks = 0; ks < 2; ++ks) {
      int row = l & 15;
      int slot = (ks * 4 + (l >> 4)) ^ (row & 7);
      pf[ks] = *(const s16x8*)(QsPs + w * 1024 + row * 64 + slot * 8);
    }

    // PV
    __builtin_amdgcn_s_setprio(1);
#pragma unroll
    for (int nf = 0; nf < 4; ++nf) {
      int row = nf * 16 + (l & 15);
#pragma unroll
      for (int ks = 0; ks < 2; ++ks) {
        int slot = (ks * 4 + (l >> 4)) ^ (row & 7);
        s16x8 vf = *(const s16x8*)(Vc + row * 64 + slot * 8);
        acc[nf] = mfma16(pf[ks], vf, acc[nf]);
      }
    }
    __builtin_amdgcn_s_setprio(0);
    __syncthreads();
  }

  int b = bh >> 4, h = bh & (NHEAD - 1);
#pragma unroll
  for (int nf = 0; nf < 4; ++nf) {
#pragma unroll
    for (int r = 0; r < 4; ++r) {
      int s = qb * 64 + w * 16 + (l >> 4) * 4 + r;
      int d = nf * 16 + (l & 15);
      float o = acc[nf][r] / lrow[r];
      ctx[((size_t)b * SEQ + s) * HID + h * HD + d] = __float2bfloat16(o);
    }
  }
}

extern "C" void kernel_launch(void* const* d_in, const int* in_sizes, int n_in,
                              void* d_out, int out_size, void* d_ws, size_t ws_size,
                              hipStream_t stream) {
  const float* X  = (const float*)d_in[0];
  const float* Wq = (const float*)d_in[1];
  const float* Wk = (const float*)d_in[2];
  const float* Wv = (const float*)d_in[3];
  const float* Wo = (const float*)d_in[4];

  char* p = (char*)d_ws;
  bf16* Xb   = (bf16*)p; p += (size_t)MROWS * HID * 2;
  bf16* Wqkv = (bf16*)p; p += (size_t)3 * HID * HID * 2;
  bf16* Wob  = (bf16*)p; p += (size_t)HID * HID * 2;
  bf16* Qb   = (bf16*)p; p += (size_t)BH * SEQ * HD * 2;
  bf16* Kb   = (bf16*)p; p += (size_t)BH * SEQ * HD * 2;
  bf16* Vb   = (bf16*)p; p += (size_t)BH * SEQ * HD * 2;
  bf16* Vtg  = (bf16*)p; p += (size_t)BH * HD * SEQ * 2;
  bf16* Cb   = (bf16*)p; p += (size_t)MROWS * HID * 2;
  float* ct  = (float*)p; p += (size_t)SEQ * 32 * 4;
  float* st  = (float*)p; p += (size_t)SEQ * 32 * 4;

  f2b_kernel<<<(MROWS * HID) / 1024, 256, 0, stream>>>(X, Xb, MROWS * HID);
  w4b_kernel<<<dim3((HID * HID) / 1024, 4), 256, 0, stream>>>(Wq, Wk, Wv, Wo, Wqkv, Wob);
  rope_tab_kernel<<<(SEQ * 32) / 256, 256, 0, stream>>>(ct, st);

  // QKV projection + fused RoPE
  gemm_bt<0><<<dim3(3 * HID / 128, MROWS / 128), 256, 0, stream>>>(
      Xb, Wqkv, nullptr, Qb, Kb, Vb, ct, st, MROWS, 3 * HID, HID);

  // V -> Vt (global transpose)
  vtrans_kernel<<<dim3(SEQ / 64, BH), 256, 0, stream>>>(Vb, Vtg);

  attn_kernel<<<dim3(SEQ / 64, BH), 256, 0, stream>>>(Qb, Kb, Vtg, Cb);

  gemm_bt<1><<<dim3(HID / 128, MROWS / 128), 256, 0, stream>>>(
      Cb, Wob, (float*)d_out, nullptr, nullptr, nullptr, nullptr, nullptr, MROWS, HID, HID);
}

// Round 3
// 153.508 us; speedup vs baseline: 1.8455x; 1.3648x over previous
//
#include <hip/hip_runtime.h>
#include <hip/hip_bf16.h>
#include <math.h>

typedef __hip_bfloat16 bf16;
typedef float f32x4 __attribute__((ext_vector_type(4)));
typedef short s16x8 __attribute__((ext_vector_type(8)));

#define NB 2
#define SEQ 2048
#define HID 1024
#define NHEAD 16
#define HD 64
#define BH (NB * NHEAD)      // 32
#define MROWS (NB * SEQ)     // 4096
// 0.125 (1/sqrt(64)) * log2(e): folded into Q so softmax runs in exp2 domain
#define QSCL 0.18033688011111793f

static __device__ __forceinline__ f32x4 mfma16(s16x8 a, s16x8 b, f32x4 c) {
  return __builtin_amdgcn_mfma_f32_16x16x32_bf16(a, b, c, 0, 0, 0);
}

static __device__ __forceinline__ void gload_lds16(const bf16* g, bf16* l) {
  __builtin_amdgcn_global_load_lds((const __attribute__((address_space(1))) void*)g,
                                   (__attribute__((address_space(3))) void*)l, 16, 0, 0);
}

static __device__ __forceinline__ unsigned pack_bf16(float a, float b) {
  __hip_bfloat162 t = __float22bfloat162_rn(float2{a, b});
  return *(unsigned*)&t;  // low 16 bits = a, high = b
}

// ---------------- fp32 -> bf16 conversion (hidden states) ----------------
__global__ __launch_bounds__(256) void f2b_kernel(const float* __restrict__ src,
                                                  bf16* __restrict__ dst, int n) {
  int i = (blockIdx.x * 256 + threadIdx.x) * 4;
  if (i >= n) return;
  float4 v = *(const float4*)(src + i);
  bf16 a0 = __float2bfloat16(v.x), a1 = __float2bfloat16(v.y);
  bf16 a2 = __float2bfloat16(v.z), a3 = __float2bfloat16(v.w);
  ushort4 u;
  u.x = *(const unsigned short*)&a0;
  u.y = *(const unsigned short*)&a1;
  u.z = *(const unsigned short*)&a2;
  u.w = *(const unsigned short*)&a3;
  *(ushort4*)(dst + i) = u;
}

// ---------------- fused weight conversions ----------------
__global__ __launch_bounds__(256) void w4b_kernel(const float* __restrict__ wq, const float* __restrict__ wk,
                                                  const float* __restrict__ wv, const float* __restrict__ wo,
                                                  bf16* __restrict__ wqkv, bf16* __restrict__ wob) {
  int wsel = blockIdx.y;
  const float* src = (wsel == 0) ? wq : (wsel == 1) ? wk : (wsel == 2) ? wv : wo;
  bf16* dst = (wsel < 3) ? (wqkv + (size_t)wsel * HID * HID) : wob;
  int i = (blockIdx.x * 256 + threadIdx.x) * 4;
  float4 v = *(const float4*)(src + i);
  bf16 a0 = __float2bfloat16(v.x), a1 = __float2bfloat16(v.y);
  bf16 a2 = __float2bfloat16(v.z), a3 = __float2bfloat16(v.w);
  ushort4 u;
  u.x = *(const unsigned short*)&a0;
  u.y = *(const unsigned short*)&a1;
  u.z = *(const unsigned short*)&a2;
  u.w = *(const unsigned short*)&a3;
  *(ushort4*)(dst + i) = u;
}

// ---------------- RoPE tables: cos/sin [SEQ][32] ----------------
__global__ __launch_bounds__(256) void rope_tab_kernel(float* __restrict__ ct, float* __restrict__ st) {
  int i = blockIdx.x * 256 + threadIdx.x;
  int s = i >> 5, j = i & 31;
  float inv = expf(-(float)(2 * j) * (9.210340371976184f / 64.0f));
  float ang = (float)s * inv;
  float sn, cs;
  sincosf(ang, &sn, &cs);
  ct[i] = cs;
  st[i] = sn;
}

// ---------------- GEMM: C[m,n] = sum_k A[m,k]*B[n,k]
// MODE 0: fused RoPE (+Q pre-scale), scatter bf16 Q/K ([BH][SEQ][HD]) and V transposed ([BH][HD][SEQ])
// MODE 1: fp32 C
template <int MODE>
__global__ __launch_bounds__(256) void gemm_bt(const bf16* __restrict__ A, const bf16* __restrict__ Bm,
                                               float* __restrict__ C,
                                               bf16* __restrict__ Qb, bf16* __restrict__ Kb,
                                               bf16* __restrict__ Vtg,
                                               const float* __restrict__ ct, const float* __restrict__ st,
                                               int M, int N, int K) {
  __shared__ __align__(16) bf16 As[128][32];
  __shared__ __align__(16) bf16 Bs[128][32];
  const int tid = threadIdx.x, lane = tid & 63, wid = tid >> 6;
  const int wm = wid >> 1, wn = wid & 1;
  const int tm = blockIdx.y * 128, tn = blockIdx.x * 128;
  const int lrow = lane >> 2;
  const int lcol = (lane & 3) * 8;

  f32x4 acc[4][4];
#pragma unroll
  for (int i = 0; i < 4; ++i)
#pragma unroll
    for (int j = 0; j < 4; ++j) acc[i][j] = (f32x4){0.f, 0.f, 0.f, 0.f};

  for (int k0 = 0; k0 < K; k0 += 32) {
    __syncthreads();
    {
      int r0 = wid * 32;
      gload_lds16(A  + (size_t)(tm + r0 +      lrow) * K + k0 + lcol, &As[r0][0]);
      gload_lds16(A  + (size_t)(tm + r0 + 16 + lrow) * K + k0 + lcol, &As[r0 + 16][0]);
      gload_lds16(Bm + (size_t)(tn + r0 +      lrow) * K + k0 + lcol, &Bs[r0][0]);
      gload_lds16(Bm + (size_t)(tn + r0 + 16 + lrow) * K + k0 + lcol, &Bs[r0 + 16][0]);
    }
    __syncthreads();
    s16x8 af[4], bfr[4];
#pragma unroll
    for (int mi = 0; mi < 4; ++mi)
      af[mi] = *(const s16x8*)&As[wm * 64 + mi * 16 + (lane & 15)][(lane >> 4) * 8];
#pragma unroll
    for (int ni = 0; ni < 4; ++ni)
      bfr[ni] = *(const s16x8*)&Bs[wn * 64 + ni * 16 + (lane & 15)][(lane >> 4) * 8];
#pragma unroll
    for (int mi = 0; mi < 4; ++mi)
#pragma unroll
      for (int ni = 0; ni < 4; ++ni)
        acc[mi][ni] = mfma16(af[mi], bfr[ni], acc[mi][ni]);
  }

  if (MODE == 0) {
    const int tblk = tn >> 10;   // 0=Q 1=K 2=V (whole block in one since 1024%128==0)
    if (tblk < 2) {
      const float scl = (tblk == 0) ? QSCL : 1.0f;
#pragma unroll
      for (int mi = 0; mi < 4; ++mi) {
#pragma unroll
        for (int r = 0; r < 4; ++r) {
          int row = tm + wm * 64 + mi * 16 + (lane >> 4) * 4 + r;
          int s = row & (SEQ - 1);
#pragma unroll
          for (int p = 0; p < 2; ++p) {
            int j = p * 16 + (lane & 15);
            float c = ct[s * 32 + j], sn = st[s * 32 + j];
            float x0 = acc[mi][p][r], x1 = acc[mi][p + 2][r];
            acc[mi][p][r]     = (x0 * c - x1 * sn) * scl;
            acc[mi][p + 2][r] = (x1 * c + x0 * sn) * scl;
          }
        }
      }
    }
  }

#pragma unroll
  for (int mi = 0; mi < 4; ++mi) {
#pragma unroll
    for (int ni = 0; ni < 4; ++ni) {
#pragma unroll
      for (int r = 0; r < 4; ++r) {
        int row = tm + wm * 64 + mi * 16 + (lane >> 4) * 4 + r;
        int col = tn + wn * 64 + ni * 16 + (lane & 15);
        float v = acc[mi][ni][r];
        if (MODE == 0) {
          int t = col >> 10, c = col & (HID - 1);
          int h = c >> 6, d = c & 63;
          int b = row >> 11, s = row & (SEQ - 1);
          size_t bh = (size_t)(b * NHEAD + h);
          if (t == 0)      Qb[(bh * SEQ + s) * HD + d]  = __float2bfloat16(v);
          else if (t == 1) Kb[(bh * SEQ + s) * HD + d]  = __float2bfloat16(v);
          else             Vtg[(bh * HD + d) * SEQ + s] = __float2bfloat16(v);
        } else {
          C[(size_t)row * N + col] = v;
        }
      }
    }
  }
}

// ---------------- Flash attention ----------------
// Q,K: [BH][SEQ][64] bf16 (Q pre-scaled by 0.125*log2e) ; Vt: [BH][64][SEQ] ;
// out ctx: [NB][SEQ][HID] bf16.
// Swapped QK^T: S = mfma(K, Q) -> lane holds q = lane&15, 16 kv values.
// K staged with bit-permuted LDS rows pi(R)=[n1 r3 r2 n0 r1 r0] so the lane's
// kv set is {8g..8g+7, 32+8g..32+8g+7} = exactly the PV A-fragment k-order:
// P never leaves registers (8 cvt_pk packs, zero shuffles, zero LDS).
__global__ __launch_bounds__(256) void attn_kernel(const bf16* __restrict__ Q, const bf16* __restrict__ K,
                                                   const bf16* __restrict__ Vt, bf16* __restrict__ ctx) {
  __shared__ __align__(16) bf16 S[8192 + 8192];  // Ks[2] | Vs[2]
  bf16* Ks = S;
  bf16* Vs = S + 8192;
  const int tid = threadIdx.x, l = tid & 63, w = tid >> 6;
  const int g = l >> 4, lq = l & 15;
  const int qb = blockIdx.x, bh = blockIdx.y;

  const bf16* Qp  = Q  + ((size_t)bh * SEQ + qb * 64) * HD;
  const bf16* Kp0 = K  + (size_t)bh * SEQ * HD;
  const bf16* Vp0 = Vt + (size_t)bh * HD * SEQ;

  // Q fragments straight to registers (B-operand layout): row w*16+lq, k = ks*32+g*8
  s16x8 qf[2];
#pragma unroll
  for (int ks = 0; ks < 2; ++ks)
    qf[ks] = *(const s16x8*)(Qp + (w * 16 + lq) * HD + ks * 32 + g * 8);

  // stage first K/V tile (K rows bit-permuted; cols XOR-swizzled via source addr)
#pragma unroll
  for (int it = 0; it < 2; ++it) {
    int cb = (it * 4 + w) * 64;
    int R = (cb + l) >> 3;
    int sc = ((l & 7) ^ (R & 7)) * 8;
    int pr = ((R & 32) >> 5) * 32 + ((R & 12) >> 2) * 8 + ((R & 16) >> 4) * 4 + (R & 3);
    gload_lds16(Kp0 + (size_t)pr * HD + sc, Ks + cb * 8);
    gload_lds16(Vp0 + (size_t)R * SEQ + sc, Vs + cb * 8);
  }
  __syncthreads();

  float m_run = -INFINITY, lsum = 0.f;
  f32x4 acc[4];
#pragma unroll
  for (int nf = 0; nf < 4; ++nf) acc[nf] = (f32x4){0.f, 0.f, 0.f, 0.f};

  const int NT = SEQ / 64;
  for (int kvt = 0; kvt < NT; ++kvt) {
    const int cur = kvt & 1;
    if (kvt + 1 < NT) {
      const bf16* Kp = Kp0 + (size_t)(kvt + 1) * 64 * HD;
      const bf16* Vp = Vp0 + (kvt + 1) * 64;
      bf16* Kd = Ks + (1 - cur) * 4096;
      bf16* Vd = Vs + (1 - cur) * 4096;
#pragma unroll
      for (int it = 0; it < 2; ++it) {
        int cb = (it * 4 + w) * 64;
        int R = (cb + l) >> 3;
        int sc = ((l & 7) ^ (R & 7)) * 8;
        int pr = ((R & 32) >> 5) * 32 + ((R & 12) >> 2) * 8 + ((R & 16) >> 4) * 4 + (R & 3);
        gload_lds16(Kp + (size_t)pr * HD + sc, Kd + cb * 8);
        gload_lds16(Vp + (size_t)R * SEQ + sc, Vd + cb * 8);
      }
    }
    const bf16* Kc = Ks + cur * 4096;
    const bf16* Vc = Vs + cur * 4096;

    // S^T = K.Q : sf[nf][r] = S[kv=pi(nf*16+4g+r)][q=lq]  (log2 domain, Q pre-scaled)
    f32x4 sf[4];
    __builtin_amdgcn_s_setprio(1);
#pragma unroll
    for (int nf = 0; nf < 4; ++nf) {
      f32x4 s = (f32x4){0.f, 0.f, 0.f, 0.f};
      int row = nf * 16 + lq;
#pragma unroll
      for (int ks = 0; ks < 2; ++ks) {
        int slot = (ks * 4 + g) ^ (row & 7);
        s16x8 kf = *(const s16x8*)(Kc + row * 64 + slot * 8);
        s = mfma16(kf, qf[ks], s);
      }
      sf[nf] = s;
    }
    __builtin_amdgcn_s_setprio(0);

    // online softmax: q = lq is lane-local; reduce over g-groups = 2 shuffles
    float pmax = sf[0][0];
#pragma unroll
    for (int nf = 0; nf < 4; ++nf)
#pragma unroll
      for (int r = 0; r < 4; ++r) pmax = fmaxf(pmax, sf[nf][r]);
    pmax = fmaxf(pmax, __shfl_xor(pmax, 16));
    pmax = fmaxf(pmax, __shfl_xor(pmax, 32));

    if (__any(pmax > m_run + 8.f)) {   // defer-max: rescale only on real growth
      float mn = fmaxf(m_run, pmax);
      float corr = __builtin_amdgcn_exp2f(m_run - mn);
      m_run = mn;
      lsum *= corr;
      float cq[4];
#pragma unroll
      for (int r = 0; r < 4; ++r) cq[r] = __shfl(corr, g * 4 + r);
#pragma unroll
      for (int nf = 0; nf < 4; ++nf)
#pragma unroll
        for (int r = 0; r < 4; ++r) acc[nf][r] *= cq[r];
    }

    float ls = 0.f;
#pragma unroll
    for (int nf = 0; nf < 4; ++nf)
#pragma unroll
      for (int r = 0; r < 4; ++r) {
        sf[nf][r] = __builtin_amdgcn_exp2f(sf[nf][r] - m_run);
        ls += sf[nf][r];
      }
    lsum += ls;

    // pack P into PV A-fragments in-register (kv order matches by construction)
    s16x8 pf[2];
    {
      unsigned pw[8];
#pragma unroll
      for (int nf = 0; nf < 4; ++nf) {
        pw[nf * 2 + 0] = pack_bf16(sf[nf][0], sf[nf][1]);
        pw[nf * 2 + 1] = pack_bf16(sf[nf][2], sf[nf][3]);
      }
      union { unsigned u[4]; s16x8 v; } c0, c1;
#pragma unroll
      for (int j = 0; j < 4; ++j) { c0.u[j] = pw[j]; c1.u[j] = pw[4 + j]; }
      pf[0] = c0.v;
      pf[1] = c1.v;
    }

    // PV: acc[nf] += P * V  (D[q][d])
    __builtin_amdgcn_s_setprio(1);
#pragma unroll
    for (int nf = 0; nf < 4; ++nf) {
      int row = nf * 16 + lq;
#pragma unroll
      for (int ks = 0; ks < 2; ++ks) {
        int slot = (ks * 4 + g) ^ (row & 7);
        s16x8 vf = *(const s16x8*)(Vc + row * 64 + slot * 8);
        acc[nf] = mfma16(pf[ks], vf, acc[nf]);
      }
    }
    __builtin_amdgcn_s_setprio(0);
    __syncthreads();
  }

  // epilogue: final l reduce (2 shuffles) + per-row broadcast
  lsum += __shfl_xor(lsum, 16);
  lsum += __shfl_xor(lsum, 32);
  float lr[4];
#pragma unroll
  for (int r = 0; r < 4; ++r) lr[r] = __shfl(lsum, g * 4 + r);

  int b = bh >> 4, h = bh & (NHEAD - 1);
#pragma unroll
  for (int nf = 0; nf < 4; ++nf) {
#pragma unroll
    for (int r = 0; r < 4; ++r) {
      int s = qb * 64 + w * 16 + g * 4 + r;
      int d = nf * 16 + lq;
      float o = acc[nf][r] / lr[r];
      ctx[((size_t)b * SEQ + s) * HID + h * HD + d] = __float2bfloat16(o);
    }
  }
}

extern "C" void kernel_launch(void* const* d_in, const int* in_sizes, int n_in,
                              void* d_out, int out_size, void* d_ws, size_t ws_size,
                              hipStream_t stream) {
  const float* X  = (const float*)d_in[0];
  const float* Wq = (const float*)d_in[1];
  const float* Wk = (const float*)d_in[2];
  const float* Wv = (const float*)d_in[3];
  const float* Wo = (const float*)d_in[4];

  char* p = (char*)d_ws;
  bf16* Xb   = (bf16*)p; p += (size_t)MROWS * HID * 2;
  bf16* Wqkv = (bf16*)p; p += (size_t)3 * HID * HID * 2;
  bf16* Wob  = (bf16*)p; p += (size_t)HID * HID * 2;
  bf16* Qb   = (bf16*)p; p += (size_t)BH * SEQ * HD * 2;
  bf16* Kb   = (bf16*)p; p += (size_t)BH * SEQ * HD * 2;
  bf16* Vtg  = (bf16*)p; p += (size_t)BH * HD * SEQ * 2;
  bf16* Cb   = (bf16*)p; p += (size_t)MROWS * HID * 2;
  float* ct  = (float*)p; p += (size_t)SEQ * 32 * 4;
  float* st  = (float*)p; p += (size_t)SEQ * 32 * 4;

  f2b_kernel<<<(MROWS * HID) / 1024, 256, 0, stream>>>(X, Xb, MROWS * HID);
  w4b_kernel<<<dim3((HID * HID) / 1024, 4), 256, 0, stream>>>(Wq, Wk, Wv, Wo, Wqkv, Wob);
  rope_tab_kernel<<<(SEQ * 32) / 256, 256, 0, stream>>>(ct, st);

  // QKV projection + fused RoPE + Q pre-scale + V direct-transpose
  gemm_bt<0><<<dim3(3 * HID / 128, MROWS / 128), 256, 0, stream>>>(
      Xb, Wqkv, nullptr, Qb, Kb, Vtg, ct, st, MROWS, 3 * HID, HID);

  attn_kernel<<<dim3(SEQ / 64, BH), 256, 0, stream>>>(Qb, Kb, Vtg, Cb);

  gemm_bt<1><<<dim3(HID / 128, MROWS / 128), 256, 0, stream>>>(
      Cb, Wob, (float*)d_out, nullptr, nullptr, nullptr, nullptr, nullptr, MROWS, HID, HID);
}

// Round 4
// 140.667 us; speedup vs baseline: 2.0139x; 1.0913x over previous
//
#include <hip/hip_runtime.h>
#include <hip/hip_bf16.h>
#include <math.h>

typedef __hip_bfloat16 bf16;
typedef float f32x4 __attribute__((ext_vector_type(4)));
typedef float f32x16 __attribute__((ext_vector_type(16)));
typedef short s16x8 __attribute__((ext_vector_type(8)));

#define NB 2
#define SEQ 2048
#define HID 1024
#define NHEAD 16
#define HD 64
#define BH (NB * NHEAD)      // 32
#define MROWS (NB * SEQ)     // 4096
// 0.125 (1/sqrt(64)) * log2(e): folded into Q so softmax runs in exp2 domain
#define QSCL 0.18033688011111793f

static __device__ __forceinline__ f32x4 mfma16(s16x8 a, s16x8 b, f32x4 c) {
  return __builtin_amdgcn_mfma_f32_16x16x32_bf16(a, b, c, 0, 0, 0);
}
static __device__ __forceinline__ f32x16 mfma32(s16x8 a, s16x8 b, f32x16 c) {
  return __builtin_amdgcn_mfma_f32_32x32x16_bf16(a, b, c, 0, 0, 0);
}

static __device__ __forceinline__ void gload_lds16(const bf16* g, bf16* l) {
  __builtin_amdgcn_global_load_lds((const __attribute__((address_space(1))) void*)g,
                                   (__attribute__((address_space(3))) void*)l, 16, 0, 0);
}

static __device__ __forceinline__ unsigned pack_bf16(float a, float b) {
  __hip_bfloat162 t = __float22bfloat162_rn(float2{a, b});
  return *(unsigned*)&t;
}

// ---------------- fused prep: X->bf16, W's->bf16, rope tables ----------------
__global__ __launch_bounds__(256) void prep_kernel(const float* __restrict__ X,
                                                   const float* __restrict__ wq, const float* __restrict__ wk,
                                                   const float* __restrict__ wv, const float* __restrict__ wo,
                                                   bf16* __restrict__ Xb, bf16* __restrict__ wqkv,
                                                   bf16* __restrict__ wob,
                                                   float* __restrict__ ct, float* __restrict__ st) {
  int bid = blockIdx.x, tid = threadIdx.x;
  if (bid < 8192) {
    const float* src;
    bf16* dst;
    int i;
    if (bid < 4096) {
      src = X; dst = Xb;
      i = (bid * 256 + tid) * 4;
    } else {
      int wsel = (bid - 4096) >> 10;
      src = (wsel == 0) ? wq : (wsel == 1) ? wk : (wsel == 2) ? wv : wo;
      dst = (wsel < 3) ? (wqkv + (size_t)wsel * HID * HID) : wob;
      i = (((bid - 4096) & 1023) * 256 + tid) * 4;
    }
    float4 v = *(const float4*)(src + i);
    bf16 a0 = __float2bfloat16(v.x), a1 = __float2bfloat16(v.y);
    bf16 a2 = __float2bfloat16(v.z), a3 = __float2bfloat16(v.w);
    ushort4 u;
    u.x = *(const unsigned short*)&a0;
    u.y = *(const unsigned short*)&a1;
    u.z = *(const unsigned short*)&a2;
    u.w = *(const unsigned short*)&a3;
    *(ushort4*)(dst + i) = u;
  } else {
    int i = (bid - 8192) * 256 + tid;   // 65536
    int s = i >> 5, j = i & 31;
    float inv = expf(-(float)(2 * j) * (9.210340371976184f / 64.0f));
    float ang = (float)s * inv;
    float sn, cs;
    sincosf(ang, &sn, &cs);
    ct[i] = cs;
    st[i] = sn;
  }
}

// ---------------- GEMM: C[m,n] = sum_k A[m,k]*B[n,k]
// MODE 0: fused RoPE (+Q pre-scale), scatter bf16 Q/K ([BH][SEQ][HD]) and V transposed ([BH][HD][SEQ])
// MODE 1: fp32 C
template <int MODE>
__global__ __launch_bounds__(256) void gemm_bt(const bf16* __restrict__ A, const bf16* __restrict__ Bm,
                                               float* __restrict__ C,
                                               bf16* __restrict__ Qb, bf16* __restrict__ Kb,
                                               bf16* __restrict__ Vtg,
                                               const float* __restrict__ ct, const float* __restrict__ st,
                                               int M, int N, int K) {
  __shared__ __align__(16) bf16 As[128][32];
  __shared__ __align__(16) bf16 Bs[128][32];
  const int tid = threadIdx.x, lane = tid & 63, wid = tid >> 6;
  const int wm = wid >> 1, wn = wid & 1;
  const int tm = blockIdx.y * 128, tn = blockIdx.x * 128;
  const int lrow = lane >> 2;
  const int lcol = (lane & 3) * 8;

  f32x4 acc[4][4];
#pragma unroll
  for (int i = 0; i < 4; ++i)
#pragma unroll
    for (int j = 0; j < 4; ++j) acc[i][j] = (f32x4){0.f, 0.f, 0.f, 0.f};

  for (int k0 = 0; k0 < K; k0 += 32) {
    __syncthreads();
    {
      int r0 = wid * 32;
      gload_lds16(A  + (size_t)(tm + r0 +      lrow) * K + k0 + lcol, &As[r0][0]);
      gload_lds16(A  + (size_t)(tm + r0 + 16 + lrow) * K + k0 + lcol, &As[r0 + 16][0]);
      gload_lds16(Bm + (size_t)(tn + r0 +      lrow) * K + k0 + lcol, &Bs[r0][0]);
      gload_lds16(Bm + (size_t)(tn + r0 + 16 + lrow) * K + k0 + lcol, &Bs[r0 + 16][0]);
    }
    __syncthreads();
    s16x8 af[4], bfr[4];
#pragma unroll
    for (int mi = 0; mi < 4; ++mi)
      af[mi] = *(const s16x8*)&As[wm * 64 + mi * 16 + (lane & 15)][(lane >> 4) * 8];
#pragma unroll
    for (int ni = 0; ni < 4; ++ni)
      bfr[ni] = *(const s16x8*)&Bs[wn * 64 + ni * 16 + (lane & 15)][(lane >> 4) * 8];
#pragma unroll
    for (int mi = 0; mi < 4; ++mi)
#pragma unroll
      for (int ni = 0; ni < 4; ++ni)
        acc[mi][ni] = mfma16(af[mi], bfr[ni], acc[mi][ni]);
  }

  if (MODE == 0) {
    const int tblk = tn >> 10;   // 0=Q 1=K 2=V
    if (tblk < 2) {
      const float scl = (tblk == 0) ? QSCL : 1.0f;
#pragma unroll
      for (int mi = 0; mi < 4; ++mi) {
#pragma unroll
        for (int r = 0; r < 4; ++r) {
          int row = tm + wm * 64 + mi * 16 + (lane >> 4) * 4 + r;
          int s = row & (SEQ - 1);
#pragma unroll
          for (int p = 0; p < 2; ++p) {
            int j = p * 16 + (lane & 15);
            float c = ct[s * 32 + j], sn = st[s * 32 + j];
            float x0 = acc[mi][p][r], x1 = acc[mi][p + 2][r];
            acc[mi][p][r]     = (x0 * c - x1 * sn) * scl;
            acc[mi][p + 2][r] = (x1 * c + x0 * sn) * scl;
          }
        }
      }
    }
  }

#pragma unroll
  for (int mi = 0; mi < 4; ++mi) {
#pragma unroll
    for (int ni = 0; ni < 4; ++ni) {
#pragma unroll
      for (int r = 0; r < 4; ++r) {
        int row = tm + wm * 64 + mi * 16 + (lane >> 4) * 4 + r;
        int col = tn + wn * 64 + ni * 16 + (lane & 15);
        float v = acc[mi][ni][r];
        if (MODE == 0) {
          int t = col >> 10, c = col & (HID - 1);
          int h = c >> 6, d = c & 63;
          int b = row >> 11, s = row & (SEQ - 1);
          size_t bh = (size_t)(b * NHEAD + h);
          if (t == 0)      Qb[(bh * SEQ + s) * HD + d]  = __float2bfloat16(v);
          else if (t == 1) Kb[(bh * SEQ + s) * HD + d]  = __float2bfloat16(v);
          else             Vtg[(bh * HD + d) * SEQ + s] = __float2bfloat16(v);
        } else {
          C[(size_t)row * N + col] = v;
        }
      }
    }
  }
}

// ---------------- Flash attention, 32x32 MFMA, QBLK=128 (32 q-rows/wave) ----------------
// Q,K: [BH][SEQ][64] bf16 (Q pre-scaled by 0.125*log2e) ; Vt: [BH][64][SEQ] ; ctx: [NB][SEQ][HID]
// Swapped QK^T (mfma(K,Q)): D[kv][q] -> q = lane&31 lane-local; kv = (reg&3)+8*(reg>>2)+4*hi.
// K staged with LDS row R holding global row sigma(R) = R with bits 2<->3 swapped, so the
// lane's 32 kv values are exactly the PV A-fragment k-order: P never leaves registers.
__global__ __launch_bounds__(256) void attn_kernel(const bf16* __restrict__ Q, const bf16* __restrict__ K,
                                                   const bf16* __restrict__ Vt, bf16* __restrict__ ctx) {
  __shared__ __align__(16) bf16 S[16384];  // Ks[2][4096] | Vs[2][4096]
  bf16* Ks = S;
  bf16* Vs = S + 8192;
  const int tid = threadIdx.x, l = tid & 63, w = tid >> 6;
  const int lq = l & 31, hi = l >> 5;

  // XCD swizzle: each XCD owns 4 consecutive heads (K/V L2-resident)
  const int id = blockIdx.x;
  const int lin = (id & 7) * 64 + (id >> 3);
  const int bh = lin >> 4, qb = lin & 15;

  const bf16* Qp  = Q  + ((size_t)bh * SEQ + qb * 128) * HD;
  const bf16* Kp0 = K  + (size_t)bh * SEQ * HD;
  const bf16* Vp0 = Vt + (size_t)bh * HD * SEQ;

  // Q fragments to registers: B-operand, row q = w*32+lq, k(d) = ks*16 + hi*8 + idx
  s16x8 qf[4];
  {
    const bf16* qr = Qp + (w * 32 + lq) * HD + hi * 8;
#pragma unroll
    for (int ks = 0; ks < 4; ++ks) qf[ks] = *(const s16x8*)(qr + ks * 16);
  }

  // hoisted staging addresses: 2 segments per thread per tile (512 segs of 16B)
  const int s0 = tid, s1 = tid + 256;
  const int R0 = s0 >> 3, R1 = s1 >> 3;
  const int c0 = ((s0 & 7) ^ (R0 & 7)) * 8;
  const int c1 = ((s1 & 7) ^ (R1 & 7)) * 8;
  const int p0 = (R0 & 51) | ((R0 & 4) << 1) | ((R0 & 8) >> 1);  // sigma(R)
  const int p1 = (R1 & 51) | ((R1 & 4) << 1) | ((R1 & 8) >> 1);
  const bf16* kS0 = Kp0 + p0 * HD + c0;
  const bf16* kS1 = Kp0 + p1 * HD + c1;
  const bf16* vS0 = Vp0 + (size_t)R0 * SEQ + c0;
  const bf16* vS1 = Vp0 + (size_t)R1 * SEQ + c1;

#define STAGE(t, b)                                        \
  do {                                                     \
    gload_lds16(kS0 + (t) * (64 * HD), Ks + (b) * 4096 + s0 * 8); \
    gload_lds16(kS1 + (t) * (64 * HD), Ks + (b) * 4096 + s1 * 8); \
    gload_lds16(vS0 + (t) * 64,        Vs + (b) * 4096 + s0 * 8); \
    gload_lds16(vS1 + (t) * 64,        Vs + (b) * 4096 + s1 * 8); \
  } while (0)

  STAGE(0, 0);
  __syncthreads();

  float m_run = -INFINITY, lsum = 0.f;
  f32x16 acc0{}, acc1{};

  const int NT = SEQ / 64;
  for (int kvt = 0; kvt < NT; ++kvt) {
    const int cur = kvt & 1;
    if (kvt + 1 < NT) STAGE(kvt + 1, cur ^ 1);
    const bf16* Kc = Ks + cur * 4096;
    const bf16* Vc = Vs + cur * 4096;

    // QK^T (swapped): sf0 = rows 0-31 (lds), sf1 = rows 32-63
    f32x16 sf0{}, sf1{};
    __builtin_amdgcn_s_setprio(1);
#pragma unroll
    for (int ks = 0; ks < 4; ++ks) {
      const int slot = (ks * 2 + hi) ^ (lq & 7);
      sf0 = mfma32(*(const s16x8*)(Kc + lq * 64 + slot * 8),        qf[ks], sf0);
      sf1 = mfma32(*(const s16x8*)(Kc + (32 + lq) * 64 + slot * 8), qf[ks], sf1);
    }
    __builtin_amdgcn_s_setprio(0);

    // online softmax: q = lq lane-local; only hi-half reduce (1 shuffle)
    float pmax = sf0[0];
#pragma unroll
    for (int i = 1; i < 16; ++i) pmax = fmaxf(pmax, sf0[i]);
#pragma unroll
    for (int i = 0; i < 16; ++i) pmax = fmaxf(pmax, sf1[i]);
    pmax = fmaxf(pmax, __shfl_xor(pmax, 32));

    if (__any(pmax > m_run + 8.f)) {
      float mn = fmaxf(m_run, pmax);
      float corr = __builtin_amdgcn_exp2f(m_run - mn);
      m_run = mn;
      lsum *= corr;
#pragma unroll
      for (int r = 0; r < 16; ++r) {
        float cr = __shfl(corr, (r & 3) + 8 * (r >> 2) + 4 * hi);
        acc0[r] *= cr;
        acc1[r] *= cr;
      }
    }

    float ls = 0.f;
#pragma unroll
    for (int i = 0; i < 16; ++i) {
      sf0[i] = __builtin_amdgcn_exp2f(sf0[i] - m_run);
      ls += sf0[i];
    }
#pragma unroll
    for (int i = 0; i < 16; ++i) {
      sf1[i] = __builtin_amdgcn_exp2f(sf1[i] - m_run);
      ls += sf1[i];
    }
    lsum += ls;   // hi-half folded once in epilogue

    // pack P into PV A-fragments (kv order matches by construction of sigma)
    s16x8 pf[4];
#pragma unroll
    for (int kt = 0; kt < 4; ++kt) {
      union { unsigned u[4]; s16x8 v; } cc;
#pragma unroll
      for (int vv = 0; vv < 4; ++vv) {
        if (kt < 2) cc.u[vv] = pack_bf16(sf0[(kt & 1) * 8 + 2 * vv], sf0[(kt & 1) * 8 + 2 * vv + 1]);
        else        cc.u[vv] = pack_bf16(sf1[(kt & 1) * 8 + 2 * vv], sf1[(kt & 1) * 8 + 2 * vv + 1]);
      }
      pf[kt] = cc.v;
    }

    // PV: acc[dblk] += P * V
    __builtin_amdgcn_s_setprio(1);
#pragma unroll
    for (int kt = 0; kt < 4; ++kt) {
      const int slot = (kt * 2 + hi) ^ (lq & 7);
      acc0 = mfma32(pf[kt], *(const s16x8*)(Vc + lq * 64 + slot * 8),        acc0);
      acc1 = mfma32(pf[kt], *(const s16x8*)(Vc + (32 + lq) * 64 + slot * 8), acc1);
    }
    __builtin_amdgcn_s_setprio(0);
    __syncthreads();
  }
#undef STAGE

  // epilogue
  lsum += __shfl_xor(lsum, 32);
  const int b = bh >> 4, h = bh & (NHEAD - 1);
#pragma unroll
  for (int r = 0; r < 16; ++r) {
    int q = (r & 3) + 8 * (r >> 2) + 4 * hi;
    float inv = 1.0f / __shfl(lsum, q);
    size_t base = ((size_t)b * SEQ + qb * 128 + w * 32 + q) * HID + h * HD + lq;
    ctx[base]      = __float2bfloat16(acc0[r] * inv);
    ctx[base + 32] = __float2bfloat16(acc1[r] * inv);
  }
}

extern "C" void kernel_launch(void* const* d_in, const int* in_sizes, int n_in,
                              void* d_out, int out_size, void* d_ws, size_t ws_size,
                              hipStream_t stream) {
  const float* X  = (const float*)d_in[0];
  const float* Wq = (const float*)d_in[1];
  const float* Wk = (const float*)d_in[2];
  const float* Wv = (const float*)d_in[3];
  const float* Wo = (const float*)d_in[4];

  char* p = (char*)d_ws;
  bf16* Xb   = (bf16*)p; p += (size_t)MROWS * HID * 2;
  bf16* Wqkv = (bf16*)p; p += (size_t)3 * HID * HID * 2;
  bf16* Wob  = (bf16*)p; p += (size_t)HID * HID * 2;
  bf16* Qb   = (bf16*)p; p += (size_t)BH * SEQ * HD * 2;
  bf16* Kb   = (bf16*)p; p += (size_t)BH * SEQ * HD * 2;
  bf16* Vtg  = (bf16*)p; p += (size_t)BH * HD * SEQ * 2;
  bf16* Cb   = (bf16*)p; p += (size_t)MROWS * HID * 2;
  float* ct  = (float*)p; p += (size_t)SEQ * 32 * 4;
  float* st  = (float*)p; p += (size_t)SEQ * 32 * 4;

  prep_kernel<<<8448, 256, 0, stream>>>(X, Wq, Wk, Wv, Wo, Xb, Wqkv, Wob, ct, st);

  // QKV projection + fused RoPE + Q pre-scale + V direct-transpose
  gemm_bt<0><<<dim3(3 * HID / 128, MROWS / 128), 256, 0, stream>>>(
      Xb, Wqkv, nullptr, Qb, Kb, Vtg, ct, st, MROWS, 3 * HID, HID);

  attn_kernel<<<dim3(512), 256, 0, stream>>>(Qb, Kb, Vtg, Cb);

  gemm_bt<1><<<dim3(HID / 128, MROWS / 128), 256, 0, stream>>>(
      Cb, Wob, (float*)d_out, nullptr, nullptr, nullptr, nullptr, nullptr, MROWS, HID, HID);
}

// Round 5
// 137.992 us; speedup vs baseline: 2.0530x; 1.0194x over previous
//
#include <hip/hip_runtime.h>
#include <hip/hip_bf16.h>
#include <math.h>

typedef __hip_bfloat16 bf16;
typedef float f32x4 __attribute__((ext_vector_type(4)));
typedef float f32x16 __attribute__((ext_vector_type(16)));
typedef short s16x8 __attribute__((ext_vector_type(8)));

#define NB 2
#define SEQ 2048
#define HID 1024
#define NHEAD 16
#define HD 64
#define BH (NB * NHEAD)      // 32
#define MROWS (NB * SEQ)     // 4096
// 0.125 (1/sqrt(64)) * log2(e): folded into Q so softmax runs in exp2 domain
#define QSCL 0.18033688011111793f

static __device__ __forceinline__ f32x4 mfma16(s16x8 a, s16x8 b, f32x4 c) {
  return __builtin_amdgcn_mfma_f32_16x16x32_bf16(a, b, c, 0, 0, 0);
}
static __device__ __forceinline__ f32x16 mfma32(s16x8 a, s16x8 b, f32x16 c) {
  return __builtin_amdgcn_mfma_f32_32x32x16_bf16(a, b, c, 0, 0, 0);
}

static __device__ __forceinline__ void gload_lds16(const bf16* g, bf16* l) {
  __builtin_amdgcn_global_load_lds((const __attribute__((address_space(1))) void*)g,
                                   (__attribute__((address_space(3))) void*)l, 16, 0, 0);
}

static __device__ __forceinline__ unsigned pack_bf16(float a, float b) {
  __hip_bfloat162 t = __float22bfloat162_rn(float2{a, b});
  return *(unsigned*)&t;
}

// ---------------- fused prep: X->bf16, W's->bf16, rope tables ----------------
__global__ __launch_bounds__(256) void prep_kernel(const float* __restrict__ X,
                                                   const float* __restrict__ wq, const float* __restrict__ wk,
                                                   const float* __restrict__ wv, const float* __restrict__ wo,
                                                   bf16* __restrict__ Xb, bf16* __restrict__ wqkv,
                                                   bf16* __restrict__ wob,
                                                   float* __restrict__ ct, float* __restrict__ st) {
  int bid = blockIdx.x, tid = threadIdx.x;
  if (bid < 8192) {
    const float* src;
    bf16* dst;
    int i;
    if (bid < 4096) {
      src = X; dst = Xb;
      i = (bid * 256 + tid) * 4;
    } else {
      int wsel = (bid - 4096) >> 10;
      src = (wsel == 0) ? wq : (wsel == 1) ? wk : (wsel == 2) ? wv : wo;
      dst = (wsel < 3) ? (wqkv + (size_t)wsel * HID * HID) : wob;
      i = (((bid - 4096) & 1023) * 256 + tid) * 4;
    }
    float4 v = *(const float4*)(src + i);
    bf16 a0 = __float2bfloat16(v.x), a1 = __float2bfloat16(v.y);
    bf16 a2 = __float2bfloat16(v.z), a3 = __float2bfloat16(v.w);
    ushort4 u;
    u.x = *(const unsigned short*)&a0;
    u.y = *(const unsigned short*)&a1;
    u.z = *(const unsigned short*)&a2;
    u.w = *(const unsigned short*)&a3;
    *(ushort4*)(dst + i) = u;
  } else {
    int i = (bid - 8192) * 256 + tid;   // 65536
    int s = i >> 5, j = i & 31;
    float inv = expf(-(float)(2 * j) * (9.210340371976184f / 64.0f));
    float ang = (float)s * inv;
    float sn, cs;
    sincosf(ang, &sn, &cs);
    ct[i] = cs;
    st[i] = sn;
  }
}

// ---------------- GEMM: C[m,n] = sum_k A[m,k]*B[n,k]
// MODE 0: fused RoPE (+Q pre-scale), scatter bf16 Q/K ([BH][SEQ][HD]) and V transposed ([BH][HD][SEQ])
// MODE 1: fp32 C
template <int MODE>
__global__ __launch_bounds__(256) void gemm_bt(const bf16* __restrict__ A, const bf16* __restrict__ Bm,
                                               float* __restrict__ C,
                                               bf16* __restrict__ Qb, bf16* __restrict__ Kb,
                                               bf16* __restrict__ Vtg,
                                               const float* __restrict__ ct, const float* __restrict__ st,
                                               int M, int N, int K) {
  __shared__ __align__(16) bf16 As[128][32];
  __shared__ __align__(16) bf16 Bs[128][32];
  const int tid = threadIdx.x, lane = tid & 63, wid = tid >> 6;
  const int wm = wid >> 1, wn = wid & 1;
  const int tm = blockIdx.y * 128, tn = blockIdx.x * 128;
  const int lrow = lane >> 2;
  const int lcol = (lane & 3) * 8;

  f32x4 acc[4][4];
#pragma unroll
  for (int i = 0; i < 4; ++i)
#pragma unroll
    for (int j = 0; j < 4; ++j) acc[i][j] = (f32x4){0.f, 0.f, 0.f, 0.f};

  for (int k0 = 0; k0 < K; k0 += 32) {
    __syncthreads();
    {
      int r0 = wid * 32;
      gload_lds16(A  + (size_t)(tm + r0 +      lrow) * K + k0 + lcol, &As[r0][0]);
      gload_lds16(A  + (size_t)(tm + r0 + 16 + lrow) * K + k0 + lcol, &As[r0 + 16][0]);
      gload_lds16(Bm + (size_t)(tn + r0 +      lrow) * K + k0 + lcol, &Bs[r0][0]);
      gload_lds16(Bm + (size_t)(tn + r0 + 16 + lrow) * K + k0 + lcol, &Bs[r0 + 16][0]);
    }
    __syncthreads();
    s16x8 af[4], bfr[4];
#pragma unroll
    for (int mi = 0; mi < 4; ++mi)
      af[mi] = *(const s16x8*)&As[wm * 64 + mi * 16 + (lane & 15)][(lane >> 4) * 8];
#pragma unroll
    for (int ni = 0; ni < 4; ++ni)
      bfr[ni] = *(const s16x8*)&Bs[wn * 64 + ni * 16 + (lane & 15)][(lane >> 4) * 8];
#pragma unroll
    for (int mi = 0; mi < 4; ++mi)
#pragma unroll
      for (int ni = 0; ni < 4; ++ni)
        acc[mi][ni] = mfma16(af[mi], bfr[ni], acc[mi][ni]);
  }

  if (MODE == 0) {
    const int tblk = tn >> 10;   // 0=Q 1=K 2=V
    if (tblk < 2) {
      const float scl = (tblk == 0) ? QSCL : 1.0f;
#pragma unroll
      for (int mi = 0; mi < 4; ++mi) {
#pragma unroll
        for (int r = 0; r < 4; ++r) {
          int row = tm + wm * 64 + mi * 16 + (lane >> 4) * 4 + r;
          int s = row & (SEQ - 1);
#pragma unroll
          for (int p = 0; p < 2; ++p) {
            int j = p * 16 + (lane & 15);
            float c = ct[s * 32 + j], sn = st[s * 32 + j];
            float x0 = acc[mi][p][r], x1 = acc[mi][p + 2][r];
            acc[mi][p][r]     = (x0 * c - x1 * sn) * scl;
            acc[mi][p + 2][r] = (x1 * c + x0 * sn) * scl;
          }
        }
      }
    }
  }

#pragma unroll
  for (int mi = 0; mi < 4; ++mi) {
#pragma unroll
    for (int ni = 0; ni < 4; ++ni) {
#pragma unroll
      for (int r = 0; r < 4; ++r) {
        int row = tm + wm * 64 + mi * 16 + (lane >> 4) * 4 + r;
        int col = tn + wn * 64 + ni * 16 + (lane & 15);
        float v = acc[mi][ni][r];
        if (MODE == 0) {
          int t = col >> 10, c = col & (HID - 1);
          int h = c >> 6, d = c & 63;
          int b = row >> 11, s = row & (SEQ - 1);
          size_t bh = (size_t)(b * NHEAD + h);
          if (t == 0)      Qb[(bh * SEQ + s) * HD + d]  = __float2bfloat16(v);
          else if (t == 1) Kb[(bh * SEQ + s) * HD + d]  = __float2bfloat16(v);
          else             Vtg[(bh * HD + d) * SEQ + s] = __float2bfloat16(v);
        } else {
          C[(size_t)row * N + col] = v;
        }
      }
    }
  }
}

// ---------------- Flash attention, 32x32 MFMA, QBLK=128, intra-block KV-split ----------------
// 512 threads = 2 groups x 4 waves. Both groups own the same 128 q-rows; group g
// processes KV tiles [g*16, g*16+16) with its own K/V double-buffers. Group 1
// deposits partial (O f32, m, l) into dead tile-LDS; group 0 merges and writes ctx.
// Swapped QK^T (mfma(K,Q)): q = lane&31 lane-local; kv = (reg&3)+8*(reg>>2)+4*hi.
// K staged with LDS row R holding global row sigma(R) (bits 2<->3 swapped) so the
// lane's 32 kv values are exactly the PV A-fragment k-order: P stays in registers.
__global__ __launch_bounds__(512, 4) void attn_kernel(const bf16* __restrict__ Q, const bf16* __restrict__ K,
                                                      const bf16* __restrict__ Vt, bf16* __restrict__ ctx) {
  __shared__ __align__(16) bf16 S[32768];  // [grp][ K dbuf 8192 | V dbuf 8192 ]
  const int tid = threadIdx.x, l = tid & 63, w = tid >> 6;
  const int lq = l & 31, hi = l >> 5;
  const int grp = w >> 2, wq = w & 3;
  const int gtid = tid & 255;

  // XCD swizzle: each XCD owns 4 consecutive heads (K/V L2-resident)
  const int id = blockIdx.x;
  const int lin = (id & 7) * 64 + (id >> 3);
  const int bh = lin >> 4, qb = lin & 15;

  const bf16* Qp  = Q  + ((size_t)bh * SEQ + qb * 128) * HD;
  const bf16* Kp0 = K  + (size_t)bh * SEQ * HD;
  const bf16* Vp0 = Vt + (size_t)bh * HD * SEQ;

  bf16* Ksg = S + grp * 16384;          // [2][4096]
  bf16* Vsg = S + grp * 16384 + 8192;   // [2][4096]

  // Q fragments to registers: B-operand, row q = wq*32+lq, k(d) = ks*16 + hi*8 + idx
  s16x8 qf[4];
  {
    const bf16* qr = Qp + (wq * 32 + lq) * HD + hi * 8;
#pragma unroll
    for (int ks = 0; ks < 4; ++ks) qf[ks] = *(const s16x8*)(qr + ks * 16);
  }

  // hoisted staging addresses: per group, 512 16B segments per tile (2 per thread)
  const int s0 = gtid, s1 = gtid + 256;
  const int R0 = s0 >> 3, R1 = s1 >> 3;
  const int c0 = ((s0 & 7) ^ (R0 & 7)) * 8;
  const int c1 = ((s1 & 7) ^ (R1 & 7)) * 8;
  const int p0 = (R0 & 51) | ((R0 & 4) << 1) | ((R0 & 8) >> 1);  // sigma(R)
  const int p1 = (R1 & 51) | ((R1 & 4) << 1) | ((R1 & 8) >> 1);
  const bf16* kS0 = Kp0 + p0 * HD + c0;
  const bf16* kS1 = Kp0 + p1 * HD + c1;
  const bf16* vS0 = Vp0 + (size_t)R0 * SEQ + c0;
  const bf16* vS1 = Vp0 + (size_t)R1 * SEQ + c1;

#define STAGE(t, b)                                                 \
  do {                                                              \
    gload_lds16(kS0 + (size_t)(t) * (64 * HD), Ksg + (b) * 4096 + s0 * 8); \
    gload_lds16(kS1 + (size_t)(t) * (64 * HD), Ksg + (b) * 4096 + s1 * 8); \
    gload_lds16(vS0 + (t) * 64,                Vsg + (b) * 4096 + s0 * 8); \
    gload_lds16(vS1 + (t) * 64,                Vsg + (b) * 4096 + s1 * 8); \
  } while (0)

  STAGE(grp * 16, 0);
  __syncthreads();

  float m_run = -INFINITY, lsum = 0.f;
  f32x16 acc0{}, acc1{};

  const int NSTEP = 16;
  for (int i = 0; i < NSTEP; ++i) {
    const int cur = i & 1;
    if (i + 1 < NSTEP) STAGE(grp * 16 + i + 1, cur ^ 1);
    const bf16* Kc = Ksg + cur * 4096;
    const bf16* Vc = Vsg + cur * 4096;

    // QK^T (swapped): sf0 = kv rows 0-31 (lds), sf1 = rows 32-63
    f32x16 sf0{}, sf1{};
    __builtin_amdgcn_s_setprio(1);
#pragma unroll
    for (int ks = 0; ks < 4; ++ks) {
      const int slot = (ks * 2 + hi) ^ (lq & 7);
      sf0 = mfma32(*(const s16x8*)(Kc + lq * 64 + slot * 8),        qf[ks], sf0);
      sf1 = mfma32(*(const s16x8*)(Kc + (32 + lq) * 64 + slot * 8), qf[ks], sf1);
    }
    __builtin_amdgcn_s_setprio(0);

    // online softmax: q = lq lane-local; only hi-half reduce (1 shuffle)
    float pmax = sf0[0];
#pragma unroll
    for (int i2 = 1; i2 < 16; ++i2) pmax = fmaxf(pmax, sf0[i2]);
#pragma unroll
    for (int i2 = 0; i2 < 16; ++i2) pmax = fmaxf(pmax, sf1[i2]);
    pmax = fmaxf(pmax, __shfl_xor(pmax, 32));

    if (__any(pmax > m_run + 8.f)) {
      float mn = fmaxf(m_run, pmax);
      float corr = __builtin_amdgcn_exp2f(m_run - mn);
      m_run = mn;
      lsum *= corr;
#pragma unroll
      for (int r = 0; r < 16; ++r) {
        float cr = __shfl(corr, (r & 3) + 8 * (r >> 2) + 4 * hi);
        acc0[r] *= cr;
        acc1[r] *= cr;
      }
    }

    float ls = 0.f;
#pragma unroll
    for (int i2 = 0; i2 < 16; ++i2) {
      sf0[i2] = __builtin_amdgcn_exp2f(sf0[i2] - m_run);
      ls += sf0[i2];
    }
#pragma unroll
    for (int i2 = 0; i2 < 16; ++i2) {
      sf1[i2] = __builtin_amdgcn_exp2f(sf1[i2] - m_run);
      ls += sf1[i2];
    }
    lsum += ls;   // hi-half folded once at the end

    // pack P into PV A-fragments (kv order matches by construction of sigma)
    s16x8 pf[4];
#pragma unroll
    for (int kt = 0; kt < 4; ++kt) {
      union { unsigned u[4]; s16x8 v; } cc;
#pragma unroll
      for (int vv = 0; vv < 4; ++vv) {
        if (kt < 2) cc.u[vv] = pack_bf16(sf0[(kt & 1) * 8 + 2 * vv], sf0[(kt & 1) * 8 + 2 * vv + 1]);
        else        cc.u[vv] = pack_bf16(sf1[(kt & 1) * 8 + 2 * vv], sf1[(kt & 1) * 8 + 2 * vv + 1]);
      }
      pf[kt] = cc.v;
    }

    // PV: acc[dblk] += P * V
    __builtin_amdgcn_s_setprio(1);
#pragma unroll
    for (int kt = 0; kt < 4; ++kt) {
      const int slot = (kt * 2 + hi) ^ (lq & 7);
      acc0 = mfma32(pf[kt], *(const s16x8*)(Vc + lq * 64 + slot * 8),        acc0);
      acc1 = mfma32(pf[kt], *(const s16x8*)(Vc + (32 + lq) * 64 + slot * 8), acc1);
    }
    __builtin_amdgcn_s_setprio(0);
    __syncthreads();
  }
#undef STAGE

  // fold hi-half of l
  lsum += __shfl_xor(lsum, 32);

  // ---- intra-block merge: group 1 deposits partials into dead tile-LDS ----
  float* Op = (float*)(S + 16384);   // 128 q x 64 d f32 (32KB, grp1 region)
  float* Mp = (float*)(S);           // 128 f32 (grp0 region, dead)
  float* Lp = Mp + 128;

  if (grp == 1) {
    if (hi == 0) {
      Mp[wq * 32 + lq] = m_run;
      Lp[wq * 32 + lq] = lsum;
    }
#pragma unroll
    for (int r = 0; r < 16; ++r) {
      int q = (r & 3) + 8 * (r >> 2) + 4 * hi;
      Op[(wq * 32 + q) * 64 + lq]      = acc0[r];
      Op[(wq * 32 + q) * 64 + 32 + lq] = acc1[r];
    }
  }
  __syncthreads();

  if (grp == 0) {
    float m1 = Mp[wq * 32 + lq], l1 = Lp[wq * 32 + lq];
    float mN = fmaxf(m_run, m1);
    float cr0 = __builtin_amdgcn_exp2f(m_run - mN);
    float cr1 = __builtin_amdgcn_exp2f(m1 - mN);
    float inv = 1.0f / (lsum * cr0 + l1 * cr1);

    const int b = bh >> 4, h = bh & (NHEAD - 1);
#pragma unroll
    for (int r = 0; r < 16; ++r) {
      int q = (r & 3) + 8 * (r >> 2) + 4 * hi;
      float c0q = __shfl(cr0, q);
      float c1q = __shfl(cr1, q);
      float invq = __shfl(inv, q);
      float o0 = (acc0[r] * c0q + Op[(wq * 32 + q) * 64 + lq]      * c1q) * invq;
      float o1 = (acc1[r] * c0q + Op[(wq * 32 + q) * 64 + 32 + lq] * c1q) * invq;
      size_t base = ((size_t)b * SEQ + qb * 128 + wq * 32 + q) * HID + h * HD + lq;
      ctx[base]      = __float2bfloat16(o0);
      ctx[base + 32] = __float2bfloat16(o1);
    }
  }
}

extern "C" void kernel_launch(void* const* d_in, const int* in_sizes, int n_in,
                              void* d_out, int out_size, void* d_ws, size_t ws_size,
                              hipStream_t stream) {
  const float* X  = (const float*)d_in[0];
  const float* Wq = (const float*)d_in[1];
  const float* Wk = (const float*)d_in[2];
  const float* Wv = (const float*)d_in[3];
  const float* Wo = (const float*)d_in[4];

  char* p = (char*)d_ws;
  bf16* Xb   = (bf16*)p; p += (size_t)MROWS * HID * 2;
  bf16* Wqkv = (bf16*)p; p += (size_t)3 * HID * HID * 2;
  bf16* Wob  = (bf16*)p; p += (size_t)HID * HID * 2;
  bf16* Qb   = (bf16*)p; p += (size_t)BH * SEQ * HD * 2;
  bf16* Kb   = (bf16*)p; p += (size_t)BH * SEQ * HD * 2;
  bf16* Vtg  = (bf16*)p; p += (size_t)BH * HD * SEQ * 2;
  bf16* Cb   = (bf16*)p; p += (size_t)MROWS * HID * 2;
  float* ct  = (float*)p; p += (size_t)SEQ * 32 * 4;
  float* st  = (float*)p; p += (size_t)SEQ * 32 * 4;

  prep_kernel<<<8448, 256, 0, stream>>>(X, Wq, Wk, Wv, Wo, Xb, Wqkv, Wob, ct, st);

  // QKV projection + fused RoPE + Q pre-scale + V direct-transpose
  gemm_bt<0><<<dim3(3 * HID / 128, MROWS / 128), 256, 0, stream>>>(
      Xb, Wqkv, nullptr, Qb, Kb, Vtg, ct, st, MROWS, 3 * HID, HID);

  attn_kernel<<<dim3(512), 512, 0, stream>>>(Qb, Kb, Vtg, Cb);

  gemm_bt<1><<<dim3(HID / 128, MROWS / 128), 256, 0, stream>>>(
      Cb, Wob, (float*)d_out, nullptr, nullptr, nullptr, nullptr, nullptr, MROWS, HID, HID);
}